// Round 1
// baseline (13886.375 us; speedup 1.0000x reference)
//
#include <hip/hip_runtime.h>
#include <hip/hip_bf16.h>
#include <math.h>

// Problem constants
#define B_  1024
#define T_  50
#define IN_ 784
#define N_  128
#define D_  40
#define H_  200
#define R_  4
#define C_  5
#define GAMMA_ 0.95f
// derived
#define XDIM_ 949            // IN + C + R*D
#define KDIM_ 1149           // IN + C (789) + H (200) + R*D (160)
#define G4H_ 800             // 4*H
#define PDIM_ 164            // R*(D+1)
#define RD_ 160              // R*D
#define OUTF_ 360            // H + R*D
#define MSZ_ 5120            // N*D

__device__ __forceinline__ float sigmoidf_(float x) { return 1.f / (1.f + expf(-x)); }

// ---------------------------------------------------------------------------
// gates = [x_t, offset_oh, h, r] @ [Wx(0:789); Wh; Wx(789:949)] + b_lstm
// A is (1024 x 1149) gathered on the fly; B is (1149 x 800). Tiled f32 GEMM.
// ---------------------------------------------------------------------------
#define TM 64
#define TN 64
#define TK 16

__global__ __launch_bounds__(256) void gates_gemm(
    const float* __restrict__ images, const int* __restrict__ labels,
    const float* __restrict__ Wx, const float* __restrict__ Wh,
    const float* __restrict__ b_lstm, const float* __restrict__ S,
    float* __restrict__ gates, int t)
{
    __shared__ float As[TK][TM + 1];
    __shared__ float Bs[TK][TN];
    const int tid = threadIdx.x;
    const int row0 = blockIdx.x * TM;   // over batch (16 blocks)
    const int col0 = blockIdx.y * TN;   // over 800 cols (13 blocks)
    const int ty = tid >> 4, tx = tid & 15;
    float acc[4][4] = {};

    for (int kt = 0; kt < KDIM_; kt += TK) {
        // stage A: 64 x 16
        #pragma unroll
        for (int i = 0; i < 4; i++) {
            int li = i * 256 + tid;
            int m = li >> 4, kk = li & 15;
            int k = kt + kk;
            int b = row0 + m;
            float v = 0.f;
            if (k < IN_) {
                v = images[((size_t)b * T_ + t) * IN_ + k];
            } else if (k < IN_ + C_) {
                v = (t > 0 && labels[b * T_ + t - 1] == (k - IN_)) ? 1.f : 0.f;
            } else if (k < IN_ + C_ + H_) {
                v = S[b * OUTF_ + (k - (IN_ + C_))];            // h
            } else if (k < KDIM_) {
                v = S[b * OUTF_ + H_ + (k - (IN_ + C_ + H_))];  // r
            }
            As[kk][m] = v;
        }
        // stage B: 16 x 64
        #pragma unroll
        for (int i = 0; i < 4; i++) {
            int li = i * 256 + tid;
            int kk = li >> 6, j = li & 63;
            int k = kt + kk;
            int col = col0 + j;
            float v = 0.f;
            if (col < G4H_) {
                if (k < IN_ + C_)            v = Wx[(size_t)k * G4H_ + col];
                else if (k < IN_ + C_ + H_)  v = Wh[(size_t)(k - (IN_ + C_)) * G4H_ + col];
                else if (k < KDIM_)          v = Wx[(size_t)(IN_ + C_ + (k - (IN_ + C_ + H_))) * G4H_ + col];
            }
            Bs[kk][j] = v;
        }
        __syncthreads();
        #pragma unroll
        for (int kk = 0; kk < TK; kk++) {
            float a[4], bv[4];
            #pragma unroll
            for (int i = 0; i < 4; i++) a[i] = As[kk][ty * 4 + i];
            #pragma unroll
            for (int j = 0; j < 4; j++) bv[j] = Bs[kk][tx * 4 + j];
            #pragma unroll
            for (int i = 0; i < 4; i++)
                #pragma unroll
                for (int j = 0; j < 4; j++) acc[i][j] += a[i] * bv[j];
        }
        __syncthreads();
    }
    #pragma unroll
    for (int i = 0; i < 4; i++) {
        int b = row0 + ty * 4 + i;
        #pragma unroll
        for (int j = 0; j < 4; j++) {
            int col = col0 + tx * 4 + j;
            if (col < G4H_) gates[(size_t)b * G4H_ + col] = acc[i][j] + b_lstm[col];
        }
    }
}

// ---------------------------------------------------------------------------
// One block per batch element: LSTM update, Wp projection, LRUA addressing,
// memory erase/write/read, logits -> probs.
// ---------------------------------------------------------------------------
__global__ __launch_bounds__(256) void step_kernel(
    const float* __restrict__ gates, float* __restrict__ S, float* __restrict__ Cst,
    float* __restrict__ Mg, float* __restrict__ wug, float* __restrict__ wrg,
    const float* __restrict__ Wp, const float* __restrict__ bp,
    const float* __restrict__ Wc, const float* __restrict__ bc,
    float* __restrict__ out, int t)
{
    const int b = blockIdx.x;
    const int tid = threadIdx.x;

    __shared__ float M_s[MSZ_];
    __shared__ float h_s[H_];
    __shared__ float k_s[RD_];
    __shared__ float sig_s[R_];
    __shared__ float kinv[R_];
    __shared__ float minv[N_];
    __shared__ float wu_s[N_];
    __shared__ int   lu_s[R_];
    __shared__ float wrn_s[R_ * N_];   // new read weights
    __shared__ float ww_s[R_ * N_];    // write weights
    __shared__ float rn_s[RD_];
    __shared__ float lg_s[C_];

    // 1) LSTM cell
    if (tid < H_) {
        const float gi = gates[(size_t)b * G4H_ + tid];
        const float gf = gates[(size_t)b * G4H_ + H_ + tid];
        const float gg = gates[(size_t)b * G4H_ + 2 * H_ + tid];
        const float go = gates[(size_t)b * G4H_ + 3 * H_ + tid];
        const float c_old = Cst[b * H_ + tid];
        const float cn = sigmoidf_(gf) * c_old + sigmoidf_(gi) * tanhf(gg);
        const float hn = sigmoidf_(go) * tanhf(cn);
        Cst[b * H_ + tid] = cn;
        h_s[tid] = hn;
        S[b * OUTF_ + tid] = hn;
    }
    for (int li = tid; li < MSZ_; li += 256) M_s[li] = Mg[(size_t)b * MSZ_ + li];
    if (tid < N_) wu_s[tid] = wug[b * N_ + tid];
    __syncthreads();

    // 2) p = h @ Wp + bp -> k (tanh), sigma (sigmoid)
    if (tid < PDIM_) {
        float acc = bp[tid];
        for (int k2 = 0; k2 < H_; k2++) acc += h_s[k2] * Wp[k2 * PDIM_ + tid];
        int r = tid / (D_ + 1), d = tid - r * (D_ + 1);
        if (d < D_) k_s[r * D_ + d] = tanhf(acc);
        else        sig_s[r] = sigmoidf_(acc);
    }
    // 3) memory row inverse norms
    if (tid >= 192 && tid < 192 + 64) { /* spread below anyway */ }
    if (tid < N_) {
        float s = 0.f;
        #pragma unroll
        for (int d = 0; d < D_; d++) { float v = M_s[tid * D_ + d]; s += v * v; }
        minv[tid] = 1.f / (sqrtf(s) + 1e-8f);
    }
    // 4) least-used top-4 (ascending by (value, index) — matches lax.top_k of -wu)
    if (tid == 192) {
        int taken0 = -1, taken1 = -1, taken2 = -1;
        for (int r = 0; r < R_; r++) {
            float bv = 3.0e38f; int bi = 0;
            for (int n = 0; n < N_; n++) {
                if (n == taken0 || n == taken1 || n == taken2) continue;
                float v = wu_s[n];
                if (v < bv) { bv = v; bi = n; }
            }
            lu_s[r] = bi;
            if (r == 0) taken0 = bi; else if (r == 1) taken1 = bi; else if (r == 2) taken2 = bi;
        }
    }
    __syncthreads();

    // 5) key inverse norms
    if (tid < R_) {
        float s = 0.f;
        #pragma unroll
        for (int d = 0; d < D_; d++) { float v = k_s[tid * D_ + d]; s += v * v; }
        kinv[tid] = 1.f / (sqrtf(s) + 1e-8f);
    }
    __syncthreads();

    // 6) cosine scores
    for (int li = tid; li < R_ * N_; li += 256) {
        int r = li >> 7, n = li & (N_ - 1);
        float s = 0.f;
        #pragma unroll
        for (int d = 0; d < D_; d++) s += k_s[r * D_ + d] * M_s[n * D_ + d];
        wrn_s[li] = s * kinv[r] * minv[n];
    }
    __syncthreads();

    // 7) softmax over N per head
    if (tid < R_) {
        float mx = -3.0e38f;
        for (int n = 0; n < N_; n++) mx = fmaxf(mx, wrn_s[tid * N_ + n]);
        float sm = 0.f;
        for (int n = 0; n < N_; n++) { float e = expf(wrn_s[tid * N_ + n] - mx); wrn_s[tid * N_ + n] = e; sm += e; }
        float inv = 1.f / sm;
        for (int n = 0; n < N_; n++) wrn_s[tid * N_ + n] *= inv;
    }
    __syncthreads();

    // 8) write weights: sigma*wr_prev + (1-sigma)*w_lu
    for (int li = tid; li < R_ * N_; li += 256) {
        int r = li >> 7, n = li & (N_ - 1);
        float wlu = (n == lu_s[0] || n == lu_s[1] || n == lu_s[2] || n == lu_s[3]) ? 1.f : 0.f;
        float sg = sig_s[r];
        ww_s[li] = sg * wrg[(size_t)b * (R_ * N_) + li] + (1.f - sg) * wlu;
    }
    __syncthreads();

    // 9) usage update + store new read weights
    if (tid < N_) {
        float acc = GAMMA_ * wu_s[tid];
        #pragma unroll
        for (int r = 0; r < R_; r++) acc += wrn_s[r * N_ + tid] + ww_s[r * N_ + tid];
        wug[b * N_ + tid] = acc;
    }
    for (int li = tid; li < R_ * N_; li += 256) wrg[(size_t)b * (R_ * N_) + li] = wrn_s[li];

    // 10) memory erase (4th least-used row) + additive write
    {
        const int lu4 = lu_s[3];
        for (int li = tid; li < MSZ_; li += 256) {
            int n = li / D_, d = li - n * D_;
            float mv = (n == lu4) ? 0.f : M_s[li];
            #pragma unroll
            for (int r = 0; r < R_; r++) mv += ww_s[r * N_ + n] * k_s[r * D_ + d];
            M_s[li] = mv;
            Mg[(size_t)b * MSZ_ + li] = mv;
        }
    }
    __syncthreads();

    // 11) read from updated memory
    if (tid < RD_) {
        int r = tid / D_, d = tid - r * D_;
        float acc = 0.f;
        for (int n = 0; n < N_; n++) acc += wrn_s[r * N_ + n] * M_s[n * D_ + d];
        rn_s[tid] = acc;
        S[b * OUTF_ + H_ + tid] = acc;
    }
    __syncthreads();

    // 12) logits = [h, r_new] @ Wc + bc
    if (tid < C_) {
        float acc = bc[tid];
        for (int j = 0; j < H_; j++)  acc += h_s[j] * Wc[j * C_ + tid];
        for (int j = 0; j < RD_; j++) acc += rn_s[j] * Wc[(H_ + j) * C_ + tid];
        lg_s[tid] = acc;
    }
    __syncthreads();
    // 13) softmax over C, write probs
    if (tid == 0) {
        float mx = lg_s[0];
        #pragma unroll
        for (int c = 1; c < C_; c++) mx = fmaxf(mx, lg_s[c]);
        float e[C_]; float sm = 0.f;
        #pragma unroll
        for (int c = 0; c < C_; c++) { e[c] = expf(lg_s[c] - mx); sm += e[c]; }
        float inv = 1.f / sm;
        #pragma unroll
        for (int c = 0; c < C_; c++) out[((size_t)b * T_ + t) * C_ + c] = e[c] * inv;
    }
}

// ---------------------------------------------------------------------------
// init state + zero the loss/acc accumulators
// ---------------------------------------------------------------------------
__global__ void init_kernel(float* S, float* Cst, float* Mg, float* wug, float* wrg, float* scal)
{
    size_t i = (size_t)blockIdx.x * blockDim.x + threadIdx.x;
    size_t stride = (size_t)gridDim.x * blockDim.x;
    for (size_t j = i; j < (size_t)B_ * MSZ_; j += stride) Mg[j] = 1e-6f;
    for (size_t j = i; j < (size_t)B_ * OUTF_; j += stride) S[j] = ((j % OUTF_) < H_) ? 0.f : 1e-6f;
    for (size_t j = i; j < (size_t)B_ * H_; j += stride) Cst[j] = 0.f;
    for (size_t j = i; j < (size_t)B_ * N_; j += stride) wug[j] = ((j & (N_ - 1)) == 0) ? 1.f : 0.f;
    for (size_t j = i; j < (size_t)B_ * R_ * N_; j += stride) wrg[j] = ((j & (N_ - 1)) == 0) ? 1.f : 0.f;
    if (i < 2) scal[i] = 0.f;
}

// ---------------------------------------------------------------------------
// loss = mean(logsumexp(probs) - probs[tgt]); acc = mean(argmax==tgt)
// ---------------------------------------------------------------------------
__global__ __launch_bounds__(256) void loss_kernel(
    const float* __restrict__ out, const int* __restrict__ labels, float* __restrict__ la)
{
    int row = blockIdx.x * 256 + threadIdx.x;
    float li = 0.f, ai = 0.f;
    if (row < B_ * T_) {
        float p[C_];
        #pragma unroll
        for (int c = 0; c < C_; c++) p[c] = out[(size_t)row * C_ + c];
        int tgt = labels[row];
        float mx = p[0];
        #pragma unroll
        for (int c = 1; c < C_; c++) mx = fmaxf(mx, p[c]);
        float sm = 0.f;
        #pragma unroll
        for (int c = 0; c < C_; c++) sm += expf(p[c] - mx);
        li = (mx + logf(sm) - p[tgt]) * (1.f / (B_ * T_));
        int pred = 0; float bv = p[0];
        #pragma unroll
        for (int c = 1; c < C_; c++) if (p[c] > bv) { bv = p[c]; pred = c; }
        ai = (pred == tgt) ? (1.f / (B_ * T_)) : 0.f;
    }
    // wave-64 reduction, one atomic per wave
    for (int off = 32; off > 0; off >>= 1) {
        li += __shfl_down(li, off);
        ai += __shfl_down(ai, off);
    }
    if ((threadIdx.x & 63) == 0) {
        atomicAdd(&la[0], li);
        atomicAdd(&la[1], ai);
    }
}

extern "C" void kernel_launch(void* const* d_in, const int* in_sizes, int n_in,
                              void* d_out, int out_size, void* d_ws, size_t ws_size,
                              hipStream_t stream)
{
    const float* images = (const float*)d_in[0];
    const int*   labels = (const int*)d_in[1];
    const float* Wx     = (const float*)d_in[2];
    const float* Wh     = (const float*)d_in[3];
    const float* b_lstm = (const float*)d_in[4];
    const float* Wp     = (const float*)d_in[5];
    const float* bp     = (const float*)d_in[6];
    const float* Wc     = (const float*)d_in[7];
    const float* bc     = (const float*)d_in[8];
    float* out = (float*)d_out;

    float* ws = (float*)d_ws;
    float* gates = ws;                          // 1024*800
    float* S     = gates + (size_t)B_ * G4H_;   // 1024*360
    float* Cst   = S + (size_t)B_ * OUTF_;      // 1024*200
    float* Mg    = Cst + (size_t)B_ * H_;       // 1024*5120
    float* wug   = Mg + (size_t)B_ * MSZ_;      // 1024*128
    float* wrg   = wug + (size_t)B_ * N_;       // 1024*512

    init_kernel<<<1024, 256, 0, stream>>>(S, Cst, Mg, wug, wrg, out + (size_t)B_ * T_ * C_);

    for (int t = 0; t < T_; t++) {
        gates_gemm<<<dim3(B_ / TM, (G4H_ + TN - 1) / TN), 256, 0, stream>>>(
            images, labels, Wx, Wh, b_lstm, S, gates, t);
        step_kernel<<<B_, 256, 0, stream>>>(
            gates, S, Cst, Mg, wug, wrg, Wp, bp, Wc, bc, out, t);
    }

    loss_kernel<<<(B_ * T_) / 256, 256, 0, stream>>>(out, labels, out + (size_t)B_ * T_ * C_);
}

// Round 2
// 3458.501 us; speedup vs baseline: 4.0151x; 4.0151x over previous
//
#include <hip/hip_runtime.h>
#include <hip/hip_bf16.h>
#include <math.h>

// Problem constants
#define B_  1024
#define T_  50
#define IN_ 784
#define N_  128
#define D_  40
#define H_  200
#define R_  4
#define C_  5
#define GAMMA_ 0.95f
#define G4H_ 800             // 4*H
#define PDIM_ 164            // R*(D+1)
#define RD_ 160              // R*D
#define OUTF_ 360            // H + R*D
#define MSZ_ 5120            // N*D
#define TC_ 10               // timestep chunk
#define KP_ 800              // padded image K (25*32)

typedef __bf16 bf16x8 __attribute__((ext_vector_type(8)));
typedef __bf16 bf16x4 __attribute__((ext_vector_type(4)));
typedef float  fx4    __attribute__((ext_vector_type(4)));

__device__ __forceinline__ float sigmoidf_(float x) { return 1.f / (1.f + expf(-x)); }

__device__ __forceinline__ void load_lds16(const void* g, void* l) {
    __builtin_amdgcn_global_load_lds(
        (const __attribute__((address_space(1))) unsigned int*)g,
        (__attribute__((address_space(3))) unsigned int*)l, 16, 0, 0);
}

// ---------------------------------------------------------------------------
// One-time packing: W2 = [Wh ; Wx(789:949)] f32, WxP = bf16 MFMA-B layout of
// Wx(0:784) padded to K=800: WxP[(kb*800+n)*32 + q*8 + j] = Wx[kb*32+q*8+j][n]
// ---------------------------------------------------------------------------
#define WXP_N 643072   // 640000 + pad (OOB-guard reads of last n-block)
__global__ __launch_bounds__(256) void pack_kernel(
    const float* __restrict__ Wx, const float* __restrict__ Wh,
    float* __restrict__ W2, __bf16* __restrict__ WxP)
{
    int idx = blockIdx.x * 256 + threadIdx.x;
    if (idx < OUTF_ * G4H_) {
        int k = idx / G4H_, col = idx - k * G4H_;
        W2[idx] = (k < H_) ? Wh[(size_t)k * G4H_ + col]
                           : Wx[(size_t)(789 + k - H_) * G4H_ + col];
    }
    if (idx < WXP_N) {
        int kb = idx / 25600, rem = idx - kb * 25600;
        int n = rem >> 5, q8 = rem & 31;
        int k = kb * 32 + q8;
        WxP[idx] = (k < IN_ && kb < 25) ? (__bf16)Wx[(size_t)k * G4H_ + n] : (__bf16)0.0f;
    }
}

// ---------------------------------------------------------------------------
// Convert a chunk of images to bf16, rows m = tloc*B + b, K padded to 800.
// ---------------------------------------------------------------------------
__global__ __launch_bounds__(256) void img_convert(
    const float* __restrict__ images, __bf16* __restrict__ img, int t0)
{
    int gi = blockIdx.x * 256 + threadIdx.x;        // index of 4-elem chunk
    if (gi * 4 >= TC_ * B_ * KP_) return;
    int m = (gi * 4) / KP_, k = (gi * 4) - m * KP_;
    int tloc = m >> 10, b = m & (B_ - 1);
    bf16x4 o;
    if (k < IN_) {
        const float4 v = *(const float4*)&images[((size_t)b * T_ + t0 + tloc) * IN_ + k];
        o[0] = (__bf16)v.x; o[1] = (__bf16)v.y; o[2] = (__bf16)v.z; o[3] = (__bf16)v.w;
    } else {
        o[0] = o[1] = o[2] = o[3] = (__bf16)0.0f;
    }
    *(bf16x4*)&img[(size_t)m * KP_ + k] = o;
}

// ---------------------------------------------------------------------------
// Gx[tloc][b][col] = img_row @ WxBf + b_lstm[col] + Wx[784+prev_label][col]
// MFMA bf16 GEMM, 128x64 tile, 4 waves (2x2), 16x16x32 frags, K=800.
// global_load_lds width-16 staging (m97 pattern).
// ---------------------------------------------------------------------------
__global__ __launch_bounds__(256) void gx_mfma(
    const __bf16* __restrict__ img, const __bf16* __restrict__ WxP,
    const int* __restrict__ labels, const float* __restrict__ Wx,
    const float* __restrict__ b_lstm, float* __restrict__ Gx, int t0)
{
    __shared__ __bf16 A_lds[4096];   // [quad][128][8] : 8 KB
    __shared__ __bf16 B_lds[2048];   // [n(64)][32]    : 4 KB

    const int tid  = threadIdx.x;
    const int lane = tid & 63, w = tid >> 6;
    const int quad = lane >> 4, ln = lane & 15;
    const int row0 = blockIdx.x * 128;
    const int n0   = blockIdx.y * 64;
    const int mw   = (w >> 1) * 64;
    const int nw   = (w & 1) * 32;

    fx4 acc[4][2];
    #pragma unroll
    for (int i = 0; i < 4; i++)
        #pragma unroll
        for (int j = 0; j < 2; j++) acc[i][j] = (fx4)0.0f;

    for (int kb = 0; kb < 25; kb++) {
        // stage A: 512 chunks of 16B; lds slot cc holds img[m=cc&127][kb*32+(cc>>7)*8 ..+7]
        #pragma unroll
        for (int p = 0; p < 2; p++) {
            int cc = p * 256 + tid;
            int m = cc & 127, q = cc >> 7;
            load_lds16(img + (size_t)(row0 + m) * KP_ + kb * 32 + q * 8,
                       &A_lds[(size_t)(p * 256 + w * 64) * 8]);
        }
        // stage B: 4 KB contiguous from packed Wx
        load_lds16(WxP + ((size_t)kb * G4H_ + n0) * 32 + (size_t)tid * 8,
                   &B_lds[(size_t)(w * 64) * 8]);
        __syncthreads();

        bf16x8 a[4], bb[2];
        #pragma unroll
        for (int mi = 0; mi < 4; mi++)
            a[mi] = *(const bf16x8*)&A_lds[(quad * 128 + mw + mi * 16 + ln) * 8];
        #pragma unroll
        for (int ni = 0; ni < 2; ni++)
            bb[ni] = *(const bf16x8*)&B_lds[(nw + ni * 16 + ln) * 32 + quad * 8];
        #pragma unroll
        for (int mi = 0; mi < 4; mi++)
            #pragma unroll
            for (int ni = 0; ni < 2; ni++)
                acc[mi][ni] = __builtin_amdgcn_mfma_f32_16x16x32_bf16(a[mi], bb[ni], acc[mi][ni], 0, 0, 0);
        __syncthreads();
    }

    // epilogue: add bias + offset-label row (f32 exact), store Gx
    #pragma unroll
    for (int mi = 0; mi < 4; mi++) {
        #pragma unroll
        for (int rr = 0; rr < 4; rr++) {
            int row = row0 + mw + mi * 16 + quad * 4 + rr;
            int tloc = row >> 10, b = row & (B_ - 1);
            int t = t0 + tloc;
            int lbl = (t > 0) ? labels[b * T_ + t - 1] : -1;
            #pragma unroll
            for (int ni = 0; ni < 2; ni++) {
                int col = n0 + nw + ni * 16 + ln;
                if (col < G4H_) {
                    float add = b_lstm[col];
                    if (lbl >= 0) add += Wx[(size_t)(IN_ + lbl) * G4H_ + col];
                    Gx[(size_t)row * G4H_ + col] = acc[mi][ni][rr] + add;
                }
            }
        }
    }
}

// ---------------------------------------------------------------------------
// gates[b][col] = Gx[tloc][b][col] + S[b][0:360] @ W2    (f32, K=360)
// 64x32 tile, TK=24 (360 = 15*24), 4x2 microtile, grid (16,25)=400 blocks.
// ---------------------------------------------------------------------------
#define RTK 24
__global__ __launch_bounds__(256) void rec_gemm(
    const float* __restrict__ S, const float* __restrict__ W2,
    const float* __restrict__ GxT, float* __restrict__ gates)
{
    __shared__ float As[RTK][64];
    __shared__ float Bs[RTK][32];
    const int tid = threadIdx.x;
    const int row0 = blockIdx.x * 64, col0 = blockIdx.y * 32;
    const int ty = tid >> 4, tx = tid & 15;
    float acc[4][2] = {};

    for (int kt = 0; kt < OUTF_; kt += RTK) {
        #pragma unroll
        for (int i = 0; i < 6; i++) {
            int li = i * 256 + tid;
            int r = li / RTK, kk = li - r * RTK;
            As[kk][r] = S[(size_t)(row0 + r) * OUTF_ + kt + kk];
        }
        #pragma unroll
        for (int i = 0; i < 3; i++) {
            int li = i * 256 + tid;
            int kk = li >> 5, c = li & 31;
            Bs[kk][c] = W2[(size_t)(kt + kk) * G4H_ + col0 + c];
        }
        __syncthreads();
        #pragma unroll
        for (int kk = 0; kk < RTK; kk++) {
            float a0 = As[kk][ty * 4], a1 = As[kk][ty * 4 + 1];
            float a2 = As[kk][ty * 4 + 2], a3 = As[kk][ty * 4 + 3];
            float b0 = Bs[kk][tx * 2], b1 = Bs[kk][tx * 2 + 1];
            acc[0][0] += a0 * b0; acc[0][1] += a0 * b1;
            acc[1][0] += a1 * b0; acc[1][1] += a1 * b1;
            acc[2][0] += a2 * b0; acc[2][1] += a2 * b1;
            acc[3][0] += a3 * b0; acc[3][1] += a3 * b1;
        }
        __syncthreads();
    }
    #pragma unroll
    for (int i = 0; i < 4; i++) {
        int b = row0 + ty * 4 + i;
        #pragma unroll
        for (int j = 0; j < 2; j++) {
            int col = col0 + tx * 2 + j;
            gates[(size_t)b * G4H_ + col] = acc[i][j] + GxT[(size_t)b * G4H_ + col];
        }
    }
}

// ---------------------------------------------------------------------------
// Per-sequence step: LSTM elementwise, Wp proj, LRUA addressing, memory
// update/read, logits->probs. Serial sections parallelized with wave shuffles.
// ---------------------------------------------------------------------------
__global__ __launch_bounds__(256) void step_kernel(
    const float* __restrict__ gates, float* __restrict__ S, float* __restrict__ Cst,
    float* __restrict__ Mg, float* __restrict__ wug, float* __restrict__ wrg,
    const float* __restrict__ Wp, const float* __restrict__ bp,
    const float* __restrict__ Wc, const float* __restrict__ bc,
    float* __restrict__ out, int t)
{
    const int b = blockIdx.x;
    const int tid = threadIdx.x;
    const int lane = tid & 63, w = tid >> 6;

    __shared__ float M_s[MSZ_];
    __shared__ float h_s[H_];
    __shared__ float k_s[RD_];
    __shared__ float sig_s[R_];
    __shared__ float wu_s[N_];
    __shared__ int   lu_s[R_];
    __shared__ float wrn_s[R_ * N_];
    __shared__ float ww_s[R_ * N_];
    __shared__ float rn_s[RD_];
    __shared__ float red[160];

    // P1: LSTM + state loads
    if (tid < H_) {
        const float gi = gates[(size_t)b * G4H_ + tid];
        const float gf = gates[(size_t)b * G4H_ + H_ + tid];
        const float gg = gates[(size_t)b * G4H_ + 2 * H_ + tid];
        const float go = gates[(size_t)b * G4H_ + 3 * H_ + tid];
        const float c_old = Cst[b * H_ + tid];
        const float cn = sigmoidf_(gf) * c_old + sigmoidf_(gi) * tanhf(gg);
        const float hn = sigmoidf_(go) * tanhf(cn);
        Cst[b * H_ + tid] = cn;
        h_s[tid] = hn;
        S[(size_t)b * OUTF_ + tid] = hn;
    }
    if (tid < N_) wu_s[tid] = wug[b * N_ + tid];
    {
        const float4* src = (const float4*)(Mg + (size_t)b * MSZ_);
        float4* dst = (float4*)M_s;
        #pragma unroll
        for (int i = 0; i < 5; i++) dst[i * 256 + tid] = src[i * 256 + tid];
    }
    __syncthreads();

    // P2: Wp projection (tid<164) || top-4 least-used (wave 3)
    if (tid < PDIM_) {
        float acc = bp[tid];
        for (int k2 = 0; k2 < H_; k2++) acc += h_s[k2] * Wp[k2 * PDIM_ + tid];
        int r = tid / (D_ + 1), d = tid - r * (D_ + 1);
        if (d < D_) k_s[r * D_ + d] = tanhf(acc);
        else        sig_s[r] = sigmoidf_(acc);
    }
    if (w == 3) {
        float v0 = wu_s[lane], v1 = wu_s[lane + 64];
        #pragma unroll
        for (int r4 = 0; r4 < R_; r4++) {
            float v; int idx;
            if (v1 < v0) { v = v1; idx = lane + 64; } else { v = v0; idx = lane; }
            #pragma unroll
            for (int off = 32; off > 0; off >>= 1) {
                float ov = __shfl_down(v, off);
                int   oi = __shfl_down(idx, off);
                if (ov < v || (ov == v && oi < idx)) { v = ov; idx = oi; }
            }
            int bi = __shfl(idx, 0);
            if (lane == 0) lu_s[r4] = bi;
            if (lane == bi) v0 = 3.0e38f;
            if (lane + 64 == bi) v1 = 3.0e38f;
        }
    }
    __syncthreads();

    // P3: raw cosine scores (row-normalized only): wrn_s[r*128+n] = dot/(||M_n||+eps)
    #pragma unroll
    for (int p = 0; p < 2; p++) {
        int li = p * 256 + tid;
        int r = li >> 7, n = li & (N_ - 1);
        float dot = 0.f, nrm = 0.f;
        #pragma unroll
        for (int d = 0; d < D_; d++) {
            float mv = M_s[n * D_ + d];
            dot += k_s[r * D_ + d] * mv;
            nrm += mv * mv;
        }
        wrn_s[li] = dot / (sqrtf(nrm) + 1e-8f);
    }
    __syncthreads();

    // P4: per-head (wave r): kinv scale, softmax over N, write weights, store wrg
    {
        const int r = w;
        float kv = (lane < D_) ? k_s[r * D_ + lane] * k_s[r * D_ + lane] : 0.f;
        #pragma unroll
        for (int off = 32; off > 0; off >>= 1) kv += __shfl_xor(kv, off);
        const float kinv = 1.f / (sqrtf(kv) + 1e-8f);

        const int n0i = lane, n1i = lane + 64;
        float s0 = wrn_s[r * N_ + n0i] * kinv;
        float s1 = wrn_s[r * N_ + n1i] * kinv;
        // write weights from prev read weights (read global before overwrite)
        const float sg = sig_s[r];
        float wlu0 = (n0i == lu_s[0] || n0i == lu_s[1] || n0i == lu_s[2] || n0i == lu_s[3]) ? 1.f : 0.f;
        float wlu1 = (n1i == lu_s[0] || n1i == lu_s[1] || n1i == lu_s[2] || n1i == lu_s[3]) ? 1.f : 0.f;
        ww_s[r * N_ + n0i] = sg * wrg[(size_t)b * (R_ * N_) + r * N_ + n0i] + (1.f - sg) * wlu0;
        ww_s[r * N_ + n1i] = sg * wrg[(size_t)b * (R_ * N_) + r * N_ + n1i] + (1.f - sg) * wlu1;
        // softmax
        float mx = fmaxf(s0, s1);
        #pragma unroll
        for (int off = 32; off > 0; off >>= 1) mx = fmaxf(mx, __shfl_xor(mx, off));
        float e0 = expf(s0 - mx), e1 = expf(s1 - mx);
        float sm = e0 + e1;
        #pragma unroll
        for (int off = 32; off > 0; off >>= 1) sm += __shfl_xor(sm, off);
        const float inv = 1.f / sm;
        e0 *= inv; e1 *= inv;
        wrn_s[r * N_ + n0i] = e0;
        wrn_s[r * N_ + n1i] = e1;
        wrg[(size_t)b * (R_ * N_) + r * N_ + n0i] = e0;
        wrg[(size_t)b * (R_ * N_) + r * N_ + n1i] = e1;
    }
    __syncthreads();

    // P5: usage update + memory erase/write
    if (tid < N_) {
        float acc = GAMMA_ * wu_s[tid];
        #pragma unroll
        for (int r = 0; r < R_; r++) acc += wrn_s[r * N_ + tid] + ww_s[r * N_ + tid];
        wug[b * N_ + tid] = acc;
    }
    {
        const int lu4 = lu_s[3];
        #pragma unroll
        for (int p = 0; p < 20; p++) {
            int li = p * 256 + tid;
            int n = li / D_, d = li - n * D_;
            float mv = (n == lu4) ? 0.f : M_s[li];
            #pragma unroll
            for (int r = 0; r < R_; r++) mv += ww_s[r * N_ + n] * k_s[r * D_ + d];
            M_s[li] = mv;
            Mg[(size_t)b * MSZ_ + li] = mv;
        }
    }
    __syncthreads();

    // P6: read vectors from updated memory
    if (tid < RD_) {
        int r = tid / D_, d = tid - r * D_;
        float acc = 0.f;
        for (int n = 0; n < N_; n++) acc += wrn_s[r * N_ + n] * M_s[n * D_ + d];
        rn_s[tid] = acc;
        S[(size_t)b * OUTF_ + H_ + tid] = acc;
    }
    __syncthreads();

    // P7: logits partials (5 cols x 32 segments)
    if (tid < 160) {
        int c = tid >> 5, seg = tid & 31;
        float acc = 0.f;
        for (int j = seg; j < OUTF_; j += 32) {
            float v = (j < H_) ? h_s[j] : rn_s[j - H_];
            acc += v * Wc[j * C_ + c];
        }
        red[tid] = acc;
    }
    __syncthreads();

    // P8: finish logits in wave 0, softmax, write probs
    if (w == 0) {
        float lg = 0.f;
        if (lane < C_) {
            lg = bc[lane];
            #pragma unroll
            for (int s = 0; s < 32; s++) lg += red[lane * 32 + s];
        }
        float l0 = __shfl(lg, 0), l1 = __shfl(lg, 1), l2 = __shfl(lg, 2);
        float l3 = __shfl(lg, 3), l4 = __shfl(lg, 4);
        if (lane == 0) {
            float mx = fmaxf(fmaxf(fmaxf(l0, l1), fmaxf(l2, l3)), l4);
            float e0 = expf(l0 - mx), e1 = expf(l1 - mx), e2 = expf(l2 - mx);
            float e3 = expf(l3 - mx), e4 = expf(l4 - mx);
            float inv = 1.f / (e0 + e1 + e2 + e3 + e4);
            float* o = out + ((size_t)b * T_ + t) * C_;
            o[0] = e0 * inv; o[1] = e1 * inv; o[2] = e2 * inv; o[3] = e3 * inv; o[4] = e4 * inv;
        }
    }
}

// ---------------------------------------------------------------------------
// init state + zero loss/acc accumulators
// ---------------------------------------------------------------------------
__global__ void init_kernel(float* S, float* Cst, float* Mg, float* wug, float* wrg, float* scal)
{
    size_t i = (size_t)blockIdx.x * blockDim.x + threadIdx.x;
    size_t stride = (size_t)gridDim.x * blockDim.x;
    for (size_t j = i; j < (size_t)B_ * MSZ_; j += stride) Mg[j] = 1e-6f;
    for (size_t j = i; j < (size_t)B_ * OUTF_; j += stride) S[j] = ((j % OUTF_) < H_) ? 0.f : 1e-6f;
    for (size_t j = i; j < (size_t)B_ * H_; j += stride) Cst[j] = 0.f;
    for (size_t j = i; j < (size_t)B_ * N_; j += stride) wug[j] = ((j & (N_ - 1)) == 0) ? 1.f : 0.f;
    for (size_t j = i; j < (size_t)B_ * R_ * N_; j += stride) wrg[j] = ((j & (N_ - 1)) == 0) ? 1.f : 0.f;
    if (i < 2) scal[i] = 0.f;
}

// ---------------------------------------------------------------------------
// loss = mean(logsumexp(probs) - probs[tgt]); acc = mean(argmax==tgt)
// ---------------------------------------------------------------------------
__global__ __launch_bounds__(256) void loss_kernel(
    const float* __restrict__ out, const int* __restrict__ labels, float* __restrict__ la)
{
    int row = blockIdx.x * 256 + threadIdx.x;
    float li = 0.f, ai = 0.f;
    if (row < B_ * T_) {
        float p[C_];
        #pragma unroll
        for (int c = 0; c < C_; c++) p[c] = out[(size_t)row * C_ + c];
        int tgt = labels[row];
        float mx = p[0];
        #pragma unroll
        for (int c = 1; c < C_; c++) mx = fmaxf(mx, p[c]);
        float sm = 0.f;
        #pragma unroll
        for (int c = 0; c < C_; c++) sm += expf(p[c] - mx);
        li = (mx + logf(sm) - p[tgt]) * (1.f / (B_ * T_));
        int pred = 0; float bv = p[0];
        #pragma unroll
        for (int c = 1; c < C_; c++) if (p[c] > bv) { bv = p[c]; pred = c; }
        ai = (pred == tgt) ? (1.f / (B_ * T_)) : 0.f;
    }
    for (int off = 32; off > 0; off >>= 1) {
        li += __shfl_down(li, off);
        ai += __shfl_down(ai, off);
    }
    if ((threadIdx.x & 63) == 0) {
        atomicAdd(&la[0], li);
        atomicAdd(&la[1], ai);
    }
}

extern "C" void kernel_launch(void* const* d_in, const int* in_sizes, int n_in,
                              void* d_out, int out_size, void* d_ws, size_t ws_size,
                              hipStream_t stream)
{
    const float* images = (const float*)d_in[0];
    const int*   labels = (const int*)d_in[1];
    const float* Wx     = (const float*)d_in[2];
    const float* Wh     = (const float*)d_in[3];
    const float* b_lstm = (const float*)d_in[4];
    const float* Wp     = (const float*)d_in[5];
    const float* bp     = (const float*)d_in[6];
    const float* Wc     = (const float*)d_in[7];
    const float* bc     = (const float*)d_in[8];
    float* out = (float*)d_out;

    float* ws = (float*)d_ws;
    float* gates = ws;                             // 1024*800          =   819200
    float* S     = gates + (size_t)B_ * G4H_;      // 1024*360          =   368640
    float* Cst   = S     + (size_t)B_ * OUTF_;     // 1024*200          =   204800
    float* Mg    = Cst   + (size_t)B_ * H_;        // 1024*5120         =  5242880
    float* wug   = Mg    + (size_t)B_ * MSZ_;      // 1024*128          =   131072
    float* wrg   = wug   + (size_t)B_ * N_;        // 1024*512          =   524288
    float* W2    = wrg   + (size_t)B_ * R_ * N_;   // 360*800           =   288000
    float* Gx    = W2    + (size_t)OUTF_ * G4H_;   // 10*1024*800       =  8192000
    __bf16* imgb = (__bf16*)(Gx + (size_t)TC_ * B_ * G4H_);  // 10*1024*800 bf16
    __bf16* WxP  = imgb + (size_t)TC_ * B_ * KP_;            // 643072 bf16
    // total ~81 MB

    pack_kernel<<<(WXP_N + 255) / 256, 256, 0, stream>>>(Wx, Wh, W2, WxP);
    init_kernel<<<1024, 256, 0, stream>>>(S, Cst, Mg, wug, wrg, out + (size_t)B_ * T_ * C_);

    for (int c = 0; c < T_ / TC_; c++) {
        const int t0 = c * TC_;
        img_convert<<<(TC_ * B_ * KP_ / 4 + 255) / 256, 256, 0, stream>>>(images, imgb, t0);
        gx_mfma<<<dim3(TC_ * B_ / 128, 13), 256, 0, stream>>>(imgb, WxP, labels, Wx, b_lstm, Gx, t0);
        for (int tl = 0; tl < TC_; tl++) {
            const int t = t0 + tl;
            rec_gemm<<<dim3(B_ / 64, G4H_ / 32), 256, 0, stream>>>(
                S, W2, Gx + (size_t)tl * B_ * G4H_, gates);
            step_kernel<<<B_, 256, 0, stream>>>(
                gates, S, Cst, Mg, wug, wrg, Wp, bp, Wc, bc, out, t);
        }
    }

    loss_kernel<<<(B_ * T_) / 256, 256, 0, stream>>>(out, labels, out + (size_t)B_ * T_ * C_);
}

// Round 3
// 3443.150 us; speedup vs baseline: 4.0330x; 1.0045x over previous
//
#include <hip/hip_runtime.h>
#include <hip/hip_bf16.h>
#include <math.h>

// Problem constants
#define B_  1024
#define T_  50
#define IN_ 784
#define N_  128
#define D_  40
#define H_  200
#define R_  4
#define C_  5
#define GAMMA_ 0.95f
#define G4H_ 800             // 4*H
#define PDIM_ 164            // R*(D+1)
#define RD_ 160              // R*D
#define OUTF_ 360            // H + R*D
#define MSZ_ 5120            // N*D
#define MST_ 41              // padded LDS stride for M rows (gcd(41,32)=1)
#define KP_ 800              // padded image K (25*32)

// recurrent GEMM hi/lo packing: K' = 36 k-blocks of 32 (12 hi + 12 lo + 12 hi)
#define AKB_ 24              // A k-blocks stored (hi 0..11, lo 12..23); block 24+i maps to i
#define BKB_ 36
#define WXP_N 643072         // 25*800*32 + pad
#define W2P_N (BKB_ * G4H_ * 32)   // 921600
#define APK_N (AKB_ * B_ * 32)     // 786432

typedef __bf16 bf16x8 __attribute__((ext_vector_type(8)));
typedef __bf16 bf16x4 __attribute__((ext_vector_type(4)));
typedef float  fx4    __attribute__((ext_vector_type(4)));

__device__ __forceinline__ float sigmoidf_(float x) { return 1.f / (1.f + expf(-x)); }

__device__ __forceinline__ void load_lds16(const void* g, void* l) {
    __builtin_amdgcn_global_load_lds(
        (const __attribute__((address_space(1))) unsigned int*)g,
        (__attribute__((address_space(3))) unsigned int*)l, 16, 0, 0);
}

// ---------------------------------------------------------------------------
// One-time packing.
// WxP: bf16 MFMA-B layout of Wx(0:784) padded to K=800:
//      WxP[(kb*800+n)*32 + q8] = Wx[kb*32+q8][n]
// W2P: hi/lo bf16 B layout of W2 = [Wh ; Wx(789:949)] (K=360 pad 384):
//      kb 0..11 -> hi, 12..23 -> hi (pairs with A lo), 24..35 -> lo
// ---------------------------------------------------------------------------
__global__ __launch_bounds__(256) void pack_kernel(
    const float* __restrict__ Wx, const float* __restrict__ Wh,
    __bf16* __restrict__ WxP, __bf16* __restrict__ W2P)
{
    int idx = blockIdx.x * 256 + threadIdx.x;
    if (idx < WXP_N) {
        int kb = idx / 25600, rem = idx - kb * 25600;
        int n = rem >> 5, q8 = rem & 31;
        int k = kb * 32 + q8;
        WxP[idx] = (k < IN_ && kb < 25) ? (__bf16)Wx[(size_t)k * G4H_ + n] : (__bf16)0.0f;
    }
    if (idx < W2P_N) {
        int kb = idx / (G4H_ * 32), rem = idx - kb * (G4H_ * 32);
        int n = rem >> 5, q8 = rem & 31;
        int kl = (kb < 12 ? kb : (kb < 24 ? kb - 12 : kb - 24)) * 32 + q8;
        __bf16 o = (__bf16)0.0f;
        if (kl < OUTF_) {
            float v = (kl < H_) ? Wh[(size_t)kl * G4H_ + n]
                                : Wx[(size_t)(789 + kl - H_) * G4H_ + n];
            __bf16 hi = (__bf16)v;
            o = (kb < 24) ? hi : (__bf16)(v - (float)hi);
        }
        W2P[idx] = o;
    }
}

// ---------------------------------------------------------------------------
// init state: memory, c, usage/read weights, Apack (h=0, r=1e-6), loss accum
// ---------------------------------------------------------------------------
__global__ void init_kernel(float* Cst, float* Mg, float* wug, float* wrg,
                            __bf16* Apack, float* scal)
{
    size_t i = (size_t)blockIdx.x * blockDim.x + threadIdx.x;
    size_t stride = (size_t)gridDim.x * blockDim.x;
    for (size_t j = i; j < (size_t)B_ * MSZ_; j += stride) Mg[j] = 1e-6f;
    for (size_t j = i; j < (size_t)B_ * H_; j += stride) Cst[j] = 0.f;
    for (size_t j = i; j < (size_t)B_ * N_; j += stride) wug[j] = ((j & (N_ - 1)) == 0) ? 1.f : 0.f;
    for (size_t j = i; j < (size_t)B_ * R_ * N_; j += stride) wrg[j] = ((j & (N_ - 1)) == 0) ? 1.f : 0.f;
    for (size_t j = i; j < (size_t)APK_N; j += stride) {
        int kb = (int)(j >> 15);
        int q8 = (int)(j & 31);
        int kl = (kb % 12) * 32 + q8;
        float v = (kl >= H_ && kl < OUTF_) ? 1e-6f : 0.f;
        __bf16 hi = (__bf16)v;
        Apack[j] = (kb < 12) ? hi : (__bf16)(v - (float)hi);
    }
    if (i < 2) scal[i] = 0.f;
}

// ---------------------------------------------------------------------------
// Convert ALL images to bf16, rows m = t*B + b, K padded to 800.
// ---------------------------------------------------------------------------
__global__ __launch_bounds__(256) void img_convert(
    const float* __restrict__ images, __bf16* __restrict__ img)
{
    long long gi = (long long)blockIdx.x * 256 + threadIdx.x;   // 4-elem chunk
    if (gi * 4 >= (long long)T_ * B_ * KP_) return;
    long long m = (gi * 4) / KP_;
    int k = (int)((gi * 4) - m * KP_);
    int t = (int)(m >> 10), b = (int)(m & (B_ - 1));
    bf16x4 o;
    if (k < IN_) {
        const float4 v = *(const float4*)&images[((size_t)b * T_ + t) * IN_ + k];
        o[0] = (__bf16)v.x; o[1] = (__bf16)v.y; o[2] = (__bf16)v.z; o[3] = (__bf16)v.w;
    } else {
        o[0] = o[1] = o[2] = o[3] = (__bf16)0.0f;
    }
    *(bf16x4*)&img[(size_t)m * KP_ + k] = o;
}

// ---------------------------------------------------------------------------
// Gx[t][b][col] = img_row @ WxBf + b_lstm[col] + Wx[784+prev_label][col]
// MFMA bf16, 128x64 tile, 4 waves (2x2), XOR-swizzled LDS chunks.
// ---------------------------------------------------------------------------
__global__ __launch_bounds__(256) void gx_mfma(
    const __bf16* __restrict__ img, const __bf16* __restrict__ WxP,
    const int* __restrict__ labels, const float* __restrict__ Wx,
    const float* __restrict__ b_lstm, float* __restrict__ Gx)
{
    __shared__ __bf16 A_lds[4096];   // [m(128)][chunk(4)] 16B chunks : 8 KB
    __shared__ __bf16 B_lds[2048];   // [n(64)][chunk(4)]            : 4 KB

    const int tid  = threadIdx.x;
    const int lane = tid & 63, w = tid >> 6;
    const int quad = lane >> 4, ln = lane & 15;
    const int swzl = (ln & 3) ^ ((ln >> 2) & 3);
    const int row0 = blockIdx.x * 128;
    const int n0   = blockIdx.y * 64;
    const int mw   = (w >> 1) * 64;
    const int nw   = (w & 1) * 32;

    fx4 acc[4][2];
    #pragma unroll
    for (int i = 0; i < 4; i++)
        #pragma unroll
        for (int j = 0; j < 2; j++) acc[i][j] = (fx4)0.0f;

    for (int kb = 0; kb < 25; kb++) {
        // stage A: 512 chunks; slot (m,c) <- img[m][kb*32 + (c^swz(m))*8 ..+7]
        #pragma unroll
        for (int p = 0; p < 2; p++) {
            int cc = p * 256 + tid;
            int m = cc >> 2, c = cc & 3;
            int q = c ^ ((m & 3) ^ ((m >> 2) & 3));
            load_lds16(img + (size_t)(row0 + m) * KP_ + kb * 32 + q * 8,
                       &A_lds[(size_t)(p * 256 + w * 64) * 8]);
        }
        // stage B: 256 chunks
        {
            int n = tid >> 2, c = tid & 3;
            int q = c ^ ((n & 3) ^ ((n >> 2) & 3));
            load_lds16(WxP + ((size_t)kb * G4H_ + n0 + n) * 32 + q * 8,
                       &B_lds[(size_t)(w * 64) * 8]);
        }
        __syncthreads();

        bf16x8 a[4], bb[2];
        #pragma unroll
        for (int mi = 0; mi < 4; mi++)
            a[mi] = *(const bf16x8*)&A_lds[((mw + mi * 16 + ln) * 4 + (quad ^ swzl)) * 8];
        #pragma unroll
        for (int ni = 0; ni < 2; ni++)
            bb[ni] = *(const bf16x8*)&B_lds[((nw + ni * 16 + ln) * 4 + (quad ^ swzl)) * 8];
        #pragma unroll
        for (int mi = 0; mi < 4; mi++)
            #pragma unroll
            for (int ni = 0; ni < 2; ni++)
                acc[mi][ni] = __builtin_amdgcn_mfma_f32_16x16x32_bf16(a[mi], bb[ni], acc[mi][ni], 0, 0, 0);
        __syncthreads();
    }

    // epilogue: add bias + offset-label row (f32 exact), store Gx
    #pragma unroll
    for (int mi = 0; mi < 4; mi++) {
        #pragma unroll
        for (int rr = 0; rr < 4; rr++) {
            int row = row0 + mw + mi * 16 + quad * 4 + rr;
            int t = row >> 10, b = row & (B_ - 1);
            int lbl = (t > 0) ? labels[b * T_ + t - 1] : -1;
            #pragma unroll
            for (int ni = 0; ni < 2; ni++) {
                int col = n0 + nw + ni * 16 + ln;
                if (col < G4H_) {
                    float add = b_lstm[col];
                    if (lbl >= 0) add += Wx[(size_t)(IN_ + lbl) * G4H_ + col];
                    Gx[(size_t)row * G4H_ + col] = acc[mi][ni][rr] + add;
                }
            }
        }
    }
}

// ---------------------------------------------------------------------------
// gates[b][col] = Gx_t[b][col] + S[b]@W2 via hi/lo bf16 MFMA, K'=1152.
// 64x32 tile, 4 waves (2x2, each 32x16), grid (16,25)=400 blocks.
// ---------------------------------------------------------------------------
__global__ __launch_bounds__(256) void rec_mfma(
    const __bf16* __restrict__ Apack, const __bf16* __restrict__ W2P,
    const float* __restrict__ Gxt, float* __restrict__ gates)
{
    __shared__ __bf16 A_lds[4096];   // [kbl(2)][row(64)][chunk(4)] : 8 KB
    __shared__ __bf16 B_lds[2048];   // [kbl(2)][n(32)][chunk(4)]   : 4 KB

    const int tid  = threadIdx.x;
    const int lane = tid & 63, w = tid >> 6;
    const int quad = lane >> 4, ln = lane & 15;
    const int swzl = (ln & 3) ^ ((ln >> 2) & 3);
    const int row0 = blockIdx.x * 64;
    const int col0 = blockIdx.y * 32;
    const int mw   = (w >> 1) * 32;
    const int nw   = (w & 1) * 16;

    fx4 acc[2];
    acc[0] = (fx4)0.0f; acc[1] = (fx4)0.0f;

    for (int it = 0; it < 18; it++) {
        // stage A: 512 chunks; slot (kbl,row,c) <- Apack[kba][row0+row][(c^swz)*8..]
        #pragma unroll
        for (int p = 0; p < 2; p++) {
            int cc = p * 256 + tid;
            int kbl = cc >> 8, row = (cc >> 2) & 63, c = cc & 3;
            int q = c ^ ((row & 3) ^ ((row >> 2) & 3));
            int kbg = it * 2 + kbl;
            int kba = (kbg < AKB_) ? kbg : kbg - AKB_;
            load_lds16(Apack + ((size_t)kba * B_ + row0 + row) * 32 + q * 8,
                       &A_lds[(size_t)(p * 256 + w * 64) * 8]);
        }
        // stage B: 256 chunks; slot (kbl,n,c)
        {
            int kbl = tid >> 7, n = (tid >> 2) & 31, c = tid & 3;
            int q = c ^ ((n & 3) ^ ((n >> 2) & 3));
            int kbg = it * 2 + kbl;
            load_lds16(W2P + ((size_t)kbg * G4H_ + col0 + n) * 32 + q * 8,
                       &B_lds[(size_t)(w * 64) * 8]);
        }
        __syncthreads();

        #pragma unroll
        for (int s = 0; s < 2; s++) {
            bf16x8 a0 = *(const bf16x8*)&A_lds[((s * 64 + mw + ln) * 4 + (quad ^ swzl)) * 8];
            bf16x8 a1 = *(const bf16x8*)&A_lds[((s * 64 + mw + 16 + ln) * 4 + (quad ^ swzl)) * 8];
            bf16x8 b0 = *(const bf16x8*)&B_lds[((s * 32 + nw + ln) * 4 + (quad ^ swzl)) * 8];
            acc[0] = __builtin_amdgcn_mfma_f32_16x16x32_bf16(a0, b0, acc[0], 0, 0, 0);
            acc[1] = __builtin_amdgcn_mfma_f32_16x16x32_bf16(a1, b0, acc[1], 0, 0, 0);
        }
        __syncthreads();
    }

    #pragma unroll
    for (int mi = 0; mi < 2; mi++) {
        #pragma unroll
        for (int rr = 0; rr < 4; rr++) {
            int row = row0 + mw + mi * 16 + quad * 4 + rr;
            int col = col0 + nw + ln;
            gates[(size_t)row * G4H_ + col] = acc[mi][rr] + Gxt[(size_t)row * G4H_ + col];
        }
    }
}

// ---------------------------------------------------------------------------
// Per-sequence step. M_s padded to stride 41 (bank-conflict-free).
// Writes h/r as hi/lo bf16 Apack fragments for the next rec_mfma.
// ---------------------------------------------------------------------------
__global__ __launch_bounds__(256) void step_kernel(
    const float* __restrict__ gates, __bf16* __restrict__ Apack, float* __restrict__ Cst,
    float* __restrict__ Mg, float* __restrict__ wug, float* __restrict__ wrg,
    const float* __restrict__ Wp, const float* __restrict__ bp,
    const float* __restrict__ Wc, const float* __restrict__ bc,
    float* __restrict__ out, int t)
{
    const int b = blockIdx.x;
    const int tid = threadIdx.x;
    const int lane = tid & 63, w = tid >> 6;

    __shared__ float M_s[N_ * MST_];   // 21 KB, stride-41
    __shared__ float h_s[H_];
    __shared__ float k_s[RD_];
    __shared__ float sig_s[R_];
    __shared__ float wu_s[N_];
    __shared__ int   lu_s[R_];
    __shared__ float wrn_s[R_ * N_];
    __shared__ float ww_s[R_ * N_];
    __shared__ float rn_s[RD_];
    __shared__ float red[160];

    // P1: LSTM + state loads
    if (tid < H_) {
        const float gi = gates[(size_t)b * G4H_ + tid];
        const float gf = gates[(size_t)b * G4H_ + H_ + tid];
        const float gg = gates[(size_t)b * G4H_ + 2 * H_ + tid];
        const float go = gates[(size_t)b * G4H_ + 3 * H_ + tid];
        const float c_old = Cst[b * H_ + tid];
        const float cn = sigmoidf_(gf) * c_old + sigmoidf_(gi) * tanhf(gg);
        const float hn = sigmoidf_(go) * tanhf(cn);
        Cst[b * H_ + tid] = cn;
        h_s[tid] = hn;
        // write h to Apack (hi/lo)
        __bf16 hi = (__bf16)hn;
        __bf16 lo = (__bf16)(hn - (float)hi);
        const int kb = tid >> 5, q8 = tid & 31;
        Apack[((size_t)kb * B_ + b) * 32 + q8] = hi;
        Apack[((size_t)(kb + 12) * B_ + b) * 32 + q8] = lo;
    }
    if (tid < N_) wu_s[tid] = wug[b * N_ + tid];
    #pragma unroll
    for (int p = 0; p < 20; p++) {
        int li = p * 256 + tid;
        int n = li / D_, d = li - n * D_;
        M_s[n * MST_ + d] = Mg[(size_t)b * MSZ_ + li];
    }
    __syncthreads();

    // P2: Wp projection (tid<164) || top-4 least-used (wave 3)
    if (tid < PDIM_) {
        float acc = bp[tid];
        #pragma unroll 4
        for (int k2 = 0; k2 < H_; k2++) acc += h_s[k2] * Wp[k2 * PDIM_ + tid];
        int r = tid / (D_ + 1), d = tid - r * (D_ + 1);
        if (d < D_) k_s[r * D_ + d] = tanhf(acc);
        else        sig_s[r] = sigmoidf_(acc);
    }
    if (w == 3) {
        float v0 = wu_s[lane], v1 = wu_s[lane + 64];
        #pragma unroll
        for (int r4 = 0; r4 < R_; r4++) {
            float v; int idx;
            if (v1 < v0) { v = v1; idx = lane + 64; } else { v = v0; idx = lane; }
            #pragma unroll
            for (int off = 32; off > 0; off >>= 1) {
                float ov = __shfl_down(v, off);
                int   oi = __shfl_down(idx, off);
                if (ov < v || (ov == v && oi < idx)) { v = ov; idx = oi; }
            }
            int bi = __shfl(idx, 0);
            if (lane == 0) lu_s[r4] = bi;
            if (lane == bi) v0 = 3.0e38f;
            if (lane + 64 == bi) v1 = 3.0e38f;
        }
    }
    __syncthreads();

    // P3: row-normalized cosine scores
    #pragma unroll
    for (int p = 0; p < 2; p++) {
        int li = p * 256 + tid;
        int r = li >> 7, n = li & (N_ - 1);
        float dot = 0.f, nrm = 0.f;
        #pragma unroll
        for (int d = 0; d < D_; d++) {
            float mv = M_s[n * MST_ + d];
            dot += k_s[r * D_ + d] * mv;
            nrm += mv * mv;
        }
        wrn_s[li] = dot / (sqrtf(nrm) + 1e-8f);
    }
    __syncthreads();

    // P4: per-head (wave r): kinv, softmax, write weights, store wrg
    {
        const int r = w;
        float kv = (lane < D_) ? k_s[r * D_ + lane] * k_s[r * D_ + lane] : 0.f;
        #pragma unroll
        for (int off = 32; off > 0; off >>= 1) kv += __shfl_xor(kv, off);
        const float kinv = 1.f / (sqrtf(kv) + 1e-8f);

        const int n0i = lane, n1i = lane + 64;
        float s0 = wrn_s[r * N_ + n0i] * kinv;
        float s1 = wrn_s[r * N_ + n1i] * kinv;
        const float sg = sig_s[r];
        float wlu0 = (n0i == lu_s[0] || n0i == lu_s[1] || n0i == lu_s[2] || n0i == lu_s[3]) ? 1.f : 0.f;
        float wlu1 = (n1i == lu_s[0] || n1i == lu_s[1] || n1i == lu_s[2] || n1i == lu_s[3]) ? 1.f : 0.f;
        ww_s[r * N_ + n0i] = sg * wrg[(size_t)b * (R_ * N_) + r * N_ + n0i] + (1.f - sg) * wlu0;
        ww_s[r * N_ + n1i] = sg * wrg[(size_t)b * (R_ * N_) + r * N_ + n1i] + (1.f - sg) * wlu1;
        float mx = fmaxf(s0, s1);
        #pragma unroll
        for (int off = 32; off > 0; off >>= 1) mx = fmaxf(mx, __shfl_xor(mx, off));
        float e0 = expf(s0 - mx), e1 = expf(s1 - mx);
        float sm = e0 + e1;
        #pragma unroll
        for (int off = 32; off > 0; off >>= 1) sm += __shfl_xor(sm, off);
        const float inv = 1.f / sm;
        e0 *= inv; e1 *= inv;
        wrn_s[r * N_ + n0i] = e0;
        wrn_s[r * N_ + n1i] = e1;
        wrg[(size_t)b * (R_ * N_) + r * N_ + n0i] = e0;
        wrg[(size_t)b * (R_ * N_) + r * N_ + n1i] = e1;
    }
    __syncthreads();

    // P5: usage update + memory erase/write
    if (tid < N_) {
        float acc = GAMMA_ * wu_s[tid];
        #pragma unroll
        for (int r = 0; r < R_; r++) acc += wrn_s[r * N_ + tid] + ww_s[r * N_ + tid];
        wug[b * N_ + tid] = acc;
    }
    {
        const int lu4 = lu_s[3];
        #pragma unroll
        for (int p = 0; p < 20; p++) {
            int li = p * 256 + tid;
            int n = li / D_, d = li - n * D_;
            float mv = (n == lu4) ? 0.f : M_s[n * MST_ + d];
            #pragma unroll
            for (int r = 0; r < R_; r++) mv += ww_s[r * N_ + n] * k_s[r * D_ + d];
            M_s[n * MST_ + d] = mv;
            Mg[(size_t)b * MSZ_ + li] = mv;
        }
    }
    __syncthreads();

    // P6: read vectors from updated memory; write r to Apack (hi/lo)
    if (tid < RD_) {
        int r = tid / D_, d = tid - r * D_;
        float acc = 0.f;
        for (int n = 0; n < N_; n++) acc += wrn_s[r * N_ + n] * M_s[n * MST_ + d];
        rn_s[tid] = acc;
        __bf16 hi = (__bf16)acc;
        __bf16 lo = (__bf16)(acc - (float)hi);
        const int kp = H_ + tid;
        const int kb = kp >> 5, q8 = kp & 31;
        Apack[((size_t)kb * B_ + b) * 32 + q8] = hi;
        Apack[((size_t)(kb + 12) * B_ + b) * 32 + q8] = lo;
    }
    __syncthreads();

    // P7: logits partials (5 cols x 32 segments)
    if (tid < 160) {
        int c = tid >> 5, seg = tid & 31;
        float acc = 0.f;
        for (int j = seg; j < OUTF_; j += 32) {
            float v = (j < H_) ? h_s[j] : rn_s[j - H_];
            acc += v * Wc[j * C_ + c];
        }
        red[tid] = acc;
    }
    __syncthreads();

    // P8: finish logits in wave 0, softmax, write probs
    if (w == 0) {
        float lg = 0.f;
        if (lane < C_) {
            lg = bc[lane];
            #pragma unroll
            for (int s = 0; s < 32; s++) lg += red[lane * 32 + s];
        }
        float l0 = __shfl(lg, 0), l1 = __shfl(lg, 1), l2 = __shfl(lg, 2);
        float l3 = __shfl(lg, 3), l4 = __shfl(lg, 4);
        if (lane == 0) {
            float mx = fmaxf(fmaxf(fmaxf(l0, l1), fmaxf(l2, l3)), l4);
            float e0 = expf(l0 - mx), e1 = expf(l1 - mx), e2 = expf(l2 - mx);
            float e3 = expf(l3 - mx), e4 = expf(l4 - mx);
            float inv = 1.f / (e0 + e1 + e2 + e3 + e4);
            float* o = out + ((size_t)b * T_ + t) * C_;
            o[0] = e0 * inv; o[1] = e1 * inv; o[2] = e2 * inv; o[3] = e3 * inv; o[4] = e4 * inv;
        }
    }
}

// ---------------------------------------------------------------------------
// loss = mean(logsumexp(probs) - probs[tgt]); acc = mean(argmax==tgt)
// ---------------------------------------------------------------------------
__global__ __launch_bounds__(256) void loss_kernel(
    const float* __restrict__ out, const int* __restrict__ labels, float* __restrict__ la)
{
    int row = blockIdx.x * 256 + threadIdx.x;
    float li = 0.f, ai = 0.f;
    if (row < B_ * T_) {
        float p[C_];
        #pragma unroll
        for (int c = 0; c < C_; c++) p[c] = out[(size_t)row * C_ + c];
        int tgt = labels[row];
        float mx = p[0];
        #pragma unroll
        for (int c = 1; c < C_; c++) mx = fmaxf(mx, p[c]);
        float sm = 0.f;
        #pragma unroll
        for (int c = 0; c < C_; c++) sm += expf(p[c] - mx);
        li = (mx + logf(sm) - p[tgt]) * (1.f / (B_ * T_));
        int pred = 0; float bv = p[0];
        #pragma unroll
        for (int c = 1; c < C_; c++) if (p[c] > bv) { bv = p[c]; pred = c; }
        ai = (pred == tgt) ? (1.f / (B_ * T_)) : 0.f;
    }
    for (int off = 32; off > 0; off >>= 1) {
        li += __shfl_down(li, off);
        ai += __shfl_down(ai, off);
    }
    if ((threadIdx.x & 63) == 0) {
        atomicAdd(&la[0], li);
        atomicAdd(&la[1], ai);
    }
}

extern "C" void kernel_launch(void* const* d_in, const int* in_sizes, int n_in,
                              void* d_out, int out_size, void* d_ws, size_t ws_size,
                              hipStream_t stream)
{
    const float* images = (const float*)d_in[0];
    const int*   labels = (const int*)d_in[1];
    const float* Wx     = (const float*)d_in[2];
    const float* Wh     = (const float*)d_in[3];
    const float* b_lstm = (const float*)d_in[4];
    const float* Wp     = (const float*)d_in[5];
    const float* bp     = (const float*)d_in[6];
    const float* Wc     = (const float*)d_in[7];
    const float* bc     = (const float*)d_in[8];
    float* out = (float*)d_out;

    float* ws = (float*)d_ws;
    float* gates = ws;                             // 1024*800
    float* Cst   = gates + (size_t)B_ * G4H_;      // 1024*200
    float* Mg    = Cst   + (size_t)B_ * H_;        // 1024*5120
    float* wug   = Mg    + (size_t)B_ * MSZ_;      // 1024*128
    float* wrg   = wug   + (size_t)B_ * N_;        // 1024*512
    float* Gx    = wrg   + (size_t)B_ * R_ * N_;   // 50*1024*800 f32 (164 MB)
    __bf16* imgb = (__bf16*)(Gx + (size_t)T_ * B_ * G4H_);   // 50*1024*800 bf16 (82 MB)
    __bf16* WxP  = imgb + (size_t)T_ * B_ * KP_;             // 643072
    __bf16* W2P  = WxP  + (size_t)WXP_N;                     // 921600
    __bf16* Apack = W2P + (size_t)W2P_N;                     // 786432
    // total ~278 MB

    pack_kernel<<<(W2P_N + 255) / 256, 256, 0, stream>>>(Wx, Wh, WxP, W2P);
    init_kernel<<<1024, 256, 0, stream>>>(Cst, Mg, wug, wrg, Apack, out + (size_t)B_ * T_ * C_);

    img_convert<<<(int)(((long long)T_ * B_ * KP_ / 4 + 255) / 256), 256, 0, stream>>>(images, imgb);
    gx_mfma<<<dim3(T_ * B_ / 128, 13), 256, 0, stream>>>(imgb, WxP, labels, Wx, b_lstm, Gx);

    for (int t = 0; t < T_; t++) {
        rec_mfma<<<dim3(B_ / 64, G4H_ / 32), 256, 0, stream>>>(
            Apack, W2P, Gx + (size_t)t * B_ * G4H_, gates);
        step_kernel<<<B_, 256, 0, stream>>>(
            gates, Apack, Cst, Mg, wug, wrg, Wp, bp, Wc, bc, out, t);
    }

    loss_kernel<<<(B_ * T_) / 256, 256, 0, stream>>>(out, labels, out + (size_t)B_ * T_ * C_);
}